// Round 11
// baseline (738.783 us; speedup 1.0000x reference)
//
#include <hip/hip_runtime.h>
#include <hip/hip_bf16.h>
#include <cstdint>

// SNN: Poisson encode (noise < x) -> [T=32] { h = sp@W1^T; v+=h; spike=(v>1); v-=spike; logits += spike@W2^T }
// B=8192, T=32, D_IN=784 (pad K to 800 = 25x32), D_H=100 (pad N to 128), D_OUT=10.
//
// v11: fused, SHARED expansion via LDS bf16 A-fragments.
//   Grid 256 x 512thr (1 block/CU). Block = 32 b-rows x 128 h x ALL t.
//   Pack phase (per t): thread owns ~6.25 8-float chunks (row-contiguous,
//   coalesced); 8 cmp -> bf16x8 -> ds_write_b128 at fragment position
//   sA[kt][row][lg*8]. Expansion happens ONCE (v10 replicated it 8x per wave
//   -> VALU throttled load issue -> 438us).
//   GEMM phase: wave = nt tile (16 h), mt=0,1: 2 ds_read_b128 + 2 wf loads +
//   4 MFMA per kt. Zero expand VALU. wf traffic 1x (minimal).
//   Schedule: loads(t+1) -> GEMM(t) (hides HBM latency) -> pack(t+1) -> barrier.
//   IF state in registers; logits epilogue in-block. No H, no bits, no scan.

typedef __attribute__((ext_vector_type(8))) short bf16x8;
typedef __attribute__((ext_vector_type(4))) float f32x4;

#define D_IN 784
#define NB 8192
#define KT 25   // K tiles of 32 (800 padded)
#define DH 100
#define ROWS 32

// ---------------- K0: pack W1 into fragment-ready bf16 hi/lo ----------------
// Fragment f = (kt*8 + nt), stored as [f][hi(512 ushorts) | lo(512 ushorts)].
// B-slot(lane l, elem j): n = nt*16 + (l&15), i = kt*32 + (l>>4)*8 + j.
__global__ void prep_w1(const float* __restrict__ W1, unsigned short* __restrict__ wf) {
    int idx = blockIdx.x * 256 + threadIdx.x;           // 25*8*64 = 12800
    if (idx >= KT * 8 * 64) return;
    int l  = idx & 63;
    int nt = (idx >> 6) & 7;
    int kt = idx >> 9;
    int n  = nt * 16 + (l & 15);
    int i0 = kt * 32 + (l >> 4) * 8;
    size_t fbase = (size_t)(kt * 8 + nt) * 1024;
    #pragma unroll
    for (int j = 0; j < 8; ++j) {
        int i = i0 + j;
        float w = (n < DH && i < D_IN) ? W1[n * D_IN + i] : 0.f;
        uint32_t ub = __float_as_uint(w);
        uint32_t rh = ub + 0x7FFFu + ((ub >> 16) & 1u);
        unsigned short h = (unsigned short)(rh >> 16);
        float hf = __uint_as_float(((uint32_t)h) << 16);
        float resid = w - hf;
        uint32_t ul = __float_as_uint(resid);
        uint32_t rl = ul + 0x7FFFu + ((ul >> 16) & 1u);
        unsigned short lo = (unsigned short)(rl >> 16);
        wf[fbase + l * 8 + j]       = h;
        wf[fbase + 512 + l * 8 + j] = lo;
    }
}

// ---------------- K1: fully-fused SNN (v11) ----------------
__global__ __launch_bounds__(512, 1) void snn_all(const float* __restrict__ x,
                                                  const float* __restrict__ noise,
                                                  const unsigned short* __restrict__ wf,
                                                  const float* __restrict__ W2,
                                                  float* __restrict__ out) {
    // A-fragment buffers: sA[buf][kt][row][32 k-elems] bf16  (2 x 51200 B)
    __shared__ __align__(16) unsigned short sA[2][KT * ROWS * 32];
    __shared__ float w2s[1000];
    __shared__ float cbuf[ROWS][132];
    const int tid  = threadIdx.x;
    const int lane = tid & 63;
    const int wave = tid >> 6;         // = nt tile 0..7 (16 h each)
    const int b0   = blockIdx.x * ROWS;
    const int u    = lane & 15;
    const int lg   = lane >> 4;

    for (int i = tid; i < 1000; i += 512) w2s[i] = W2[i];

    // ---- chunk assignment: slot s = p*512 + tid, s < 3200 ----
    // row = s/100, c = s%100, kt = c>>2, lg_c = c&3; chunk = 8 floats at
    // row*784 + c*8 (fully linear per row). Pad: kt==24 && lg_c>=2.
    int   srow[7], sdst[7];
    bool  sval[7], spad[7];
    int   sfo[7];
    #pragma unroll
    for (int p = 0; p < 7; ++p) {
        const int s = p * 512 + tid;
        sval[p] = (s < 3200);
        const int row = s / 100;
        const int c   = s - row * 100;
        const int kt  = c >> 2;
        const int lgc = c & 3;
        spad[p] = (kt == 24 && lgc >= 2);
        srow[p] = row;
        sfo[p]  = row * D_IN + c * 8;                  // float offset (pad: unused)
        sdst[p] = kt * (ROWS * 32) + row * 32 + lgc * 8;  // ushort offset in sA[buf]
    }

    const float* xb     = x + (size_t)b0 * D_IN;
    const float* nbase  = noise + (size_t)b0 * D_IN;
    const size_t tstride = (size_t)NB * D_IN;

    // x chunks in registers (loaded once)
    float4 xr[7][2];
    #pragma unroll
    for (int p = 0; p < 7; ++p)
        if (sval[p] && !spad[p]) {
            xr[p][0] = *reinterpret_cast<const float4*>(xb + sfo[p]);
            xr[p][1] = *reinterpret_cast<const float4*>(xb + sfo[p] + 4);
        }

    float4 tmp[7][2];
    auto LOAD = [&](int t) {
        const float* np_ = nbase + (size_t)t * tstride;
        #pragma unroll
        for (int p = 0; p < 7; ++p)
            if (sval[p] && !spad[p]) {
                tmp[p][0] = *reinterpret_cast<const float4*>(np_ + sfo[p]);
                tmp[p][1] = *reinterpret_cast<const float4*>(np_ + sfo[p] + 4);
            }
    };
    auto PACK = [&](int buf) {
        unsigned short* dst = &sA[buf][0];
        #pragma unroll
        for (int p = 0; p < 7; ++p)
            if (sval[p]) {
                uint4 w = make_uint4(0u, 0u, 0u, 0u);
                if (!spad[p]) {
                    const float4 n0 = tmp[p][0], n1 = tmp[p][1];
                    const float4 x0 = xr[p][0],  x1 = xr[p][1];
                    w.x = (n0.x < x0.x ? 0x3F80u : 0u) | (n0.y < x0.y ? 0x3F800000u : 0u);
                    w.y = (n0.z < x0.z ? 0x3F80u : 0u) | (n0.w < x0.w ? 0x3F800000u : 0u);
                    w.z = (n1.x < x1.x ? 0x3F80u : 0u) | (n1.y < x1.y ? 0x3F800000u : 0u);
                    w.w = (n1.z < x1.z ? 0x3F80u : 0u) | (n1.w < x1.w ? 0x3F800000u : 0u);
                }
                *reinterpret_cast<uint4*>(dst + sdst[p]) = w;
            }
    };

    // prologue: t=0 -> buf 0
    LOAD(0);
    PACK(0);
    __syncthreads();

    f32x4 v[2], cnt[2];
    #pragma unroll
    for (int m = 0; m < 2; ++m) { v[m] = (f32x4){0,0,0,0}; cnt[m] = (f32x4){0,0,0,0}; }

    for (int t = 0; t < 32; ++t) {
        const int cur = t & 1;
        if (t < 31) LOAD(t + 1);                       // issue early; GEMM hides latency

        // ---- GEMM(t): wave = nt, mt = 0,1 ----
        const unsigned short* sa = &sA[cur][0];
        f32x4 acc0 = (f32x4){0,0,0,0}, acc1 = (f32x4){0,0,0,0};
        #pragma unroll
        for (int kt = 0; kt < KT; ++kt) {
            const bf16x8 a0 = *reinterpret_cast<const bf16x8*>(sa + kt * (ROWS * 32) + u * 32 + lg * 8);
            const bf16x8 a1 = *reinterpret_cast<const bf16x8*>(sa + kt * (ROWS * 32) + (u + 16) * 32 + lg * 8);
            const size_t fo = (size_t)(kt * 8 + wave) * 1024 + lane * 8;
            const bf16x8 bhi = *reinterpret_cast<const bf16x8*>(wf + fo);
            const bf16x8 blo = *reinterpret_cast<const bf16x8*>(wf + fo + 512);
            acc0 = __builtin_amdgcn_mfma_f32_16x16x32_bf16(a0, bhi, acc0, 0, 0, 0);
            acc0 = __builtin_amdgcn_mfma_f32_16x16x32_bf16(a0, blo, acc0, 0, 0, 0);
            acc1 = __builtin_amdgcn_mfma_f32_16x16x32_bf16(a1, bhi, acc1, 0, 0, 0);
            acc1 = __builtin_amdgcn_mfma_f32_16x16x32_bf16(a1, blo, acc1, 0, 0, 0);
        }

        // ---- IF update (exact reference semantics) ----
        #pragma unroll
        for (int r = 0; r < 4; ++r) {
            const float v0 = v[0][r] + acc0[r];
            const float s0 = (v0 - 1.0f > 0.0f) ? 1.0f : 0.0f;
            v[0][r] = v0 - s0;  cnt[0][r] += s0;
            const float v1 = v[1][r] + acc1[r];
            const float s1 = (v1 - 1.0f > 0.0f) ? 1.0f : 0.0f;
            v[1][r] = v1 - s1;  cnt[1][r] += s1;
        }

        if (t < 31) PACK(cur ^ 1);                     // waits tmp (arrived during GEMM)
        __syncthreads();                               // pack visible; sA[cur] reads done
    }

    // ---- epilogue: cnt -> cbuf, logits = cnt @ W2^T ----
    // C/D layout: col = u (h = wave*16+u), row = m*16 + lg*4 + r
    #pragma unroll
    for (int m = 0; m < 2; ++m)
        #pragma unroll
        for (int r = 0; r < 4; ++r)
            cbuf[m * 16 + lg * 4 + r][wave * 16 + u] = cnt[m][r];
    __syncthreads();
    {
        const int row = tid >> 4, o = tid & 15;
        if (o < 10) {
            float s = 0.f;
            for (int hh = 0; hh < DH; ++hh) s += cbuf[row][hh] * w2s[o * DH + hh];
            out[(size_t)(b0 + row) * 10 + o] = s;
        }
    }
}

extern "C" void kernel_launch(void* const* d_in, const int* in_sizes, int n_in,
                              void* d_out, int out_size, void* d_ws, size_t ws_size,
                              hipStream_t stream) {
    const float* x     = (const float*)d_in[0];   // [8192,784]
    const float* noise = (const float*)d_in[1];   // [32,8192,784]
    const float* W1    = (const float*)d_in[2];   // [100,784]
    const float* W2    = (const float*)d_in[3];   // [10,100]
    float* out = (float*)d_out;                   // [8192,10]

    unsigned short* wf = (unsigned short*)d_ws;   // 400 KB W1 frags

    prep_w1<<<50, 256, 0, stream>>>(W1, wf);
    snn_all<<<256, 512, 0, stream>>>(x, noise, wf, W2, out);
}

// Round 12
// 317.258 us; speedup vs baseline: 2.3286x; 2.3286x over previous
//
#include <hip/hip_runtime.h>
#include <hip/hip_bf16.h>
#include <cstdint>

// SNN: Poisson encode (noise < x) -> [T=32] { h = sp@W1^T; v+=h; spike=(v>1); v-=spike; logits += spike@W2^T }
// B=8192, T=32, D_IN=784 (pad K to 800 = 25x32), D_H=100 (pad N to 128), D_OUT=10.
//
// v12: v7 shape (many independent blocks, pack->barrier->gemm) + t-PAIR blocks.
//   Grid 1024 = 16 t-pairs x 64 btiles, 512 thr (8 waves, 2M x 4N).
//   Pack: per pass load x once + noise[t0],[t1] (x traffic & issue /2 per t),
//         ballot-pack both into sB[2] (v9 bit mapping, verified).
//   GEMM: per kt load wf fragment once, MFMA both t's (wf traffic /2 per t).
//   acc[2][4][2] f32x4 = 64 VGPR. Noise loads nontemporal (protect L2 x/wf).
//   H [b][t][100] transposed; snn_scan unchanged (v6-verbatim).

typedef __attribute__((ext_vector_type(8))) short bf16x8;
typedef __attribute__((ext_vector_type(4))) float f32x4;

#define D_IN 784
#define NB 8192
#define KT 25   // K tiles of 32 (800 padded)
#define DH 100

// ---------------- K0: pack W1 into fragment-ready bf16 hi/lo ----------------
// Fragment f = (kt*8 + nt), stored as [f][hi(512 ushorts) | lo(512 ushorts)].
// B-slot(lane l, elem j): n = nt*16 + (l&15), i = kt*32 + (l>>4)*8 + j.
__global__ void prep_w1(const float* __restrict__ W1, unsigned short* __restrict__ wf) {
    int idx = blockIdx.x * 256 + threadIdx.x;           // 25*8*64 = 12800
    if (idx >= KT * 8 * 64) return;
    int l  = idx & 63;
    int nt = (idx >> 6) & 7;
    int kt = idx >> 9;
    int n  = nt * 16 + (l & 15);
    int i0 = kt * 32 + (l >> 4) * 8;
    size_t fbase = (size_t)(kt * 8 + nt) * 1024;
    #pragma unroll
    for (int j = 0; j < 8; ++j) {
        int i = i0 + j;
        float w = (n < DH && i < D_IN) ? W1[n * D_IN + i] : 0.f;
        uint32_t ub = __float_as_uint(w);
        uint32_t rh = ub + 0x7FFFu + ((ub >> 16) & 1u);
        unsigned short h = (unsigned short)(rh >> 16);
        float hf = __uint_as_float(((uint32_t)h) << 16);
        float resid = w - hf;
        uint32_t ul = __float_as_uint(resid);
        uint32_t rl = ul + 0x7FFFu + ((ul >> 16) & 1u);
        unsigned short lo = (unsigned short)(rl >> 16);
        wf[fbase + l * 8 + j]       = h;
        wf[fbase + 512 + l * 8 + j] = lo;
    }
}

__device__ __forceinline__ f32x4 ldnt(const float* p) {
    return __builtin_nontemporal_load(reinterpret_cast<const f32x4*>(p));
}
__device__ __forceinline__ f32x4 ld(const float* p) {
    return *reinterpret_cast<const f32x4*>(p);
}

// ---------------- K1: t-pair pack+GEMM ----------------
// Pack mapping (v9-verbatim, 512 thr, 49 passes x 512 f4 = 25088 = 128x196 exact):
// pass p: thread owns f4 = p*512+tid; ushort-group g = p*128 + wave*16 + u,
// row = g/49, colu = g%49; stored bit q <-> float offset f: q = 4*(f&3)+(f>>2).
// Expand (verified): lg=lane>>4, qe0=(lg&1)*2+(lg>>1)*16; dword d:
// qe = qe0 + (d&1)*8 + (d>>1); bits {qe, qe+4}.
__global__ __launch_bounds__(512) void snn_gemm2(const float* __restrict__ x,
                                                 const float* __restrict__ noise,
                                                 const unsigned short* __restrict__ wf,
                                                 float* __restrict__ H) {
    __shared__ __align__(4) unsigned short sB[2][128 * 50];   // 2 x 12.8KB
    const int tid  = threadIdx.x;
    const int lane = tid & 63;
    const int wave = tid >> 6;
    const int L     = blockIdx.x;
    const int btile = (L & 7) * 8 + ((L >> 3) & 7);   // XCD swizzle: x slice 3.2MB/XCD
    const int tp    = L >> 6;                          // t-pair 0..15
    const int b0    = btile * 128;
    const int u     = lane & 15;
    const int lg    = lane >> 4;
    const int Mhalf = wave >> 2;       // 0..1 (64 rows each)
    const int Nq    = wave & 3;        // 0..3 (ntiles Nq*2, Nq*2+1)

    if (tid < 256) sB[tid >> 7][(tid & 127) * 50 + 49] = 0;   // k-pad both tiles

    const float* xb    = x + (size_t)b0 * D_IN;
    const float* nb0   = noise + (size_t)(2 * tp) * ((size_t)NB * D_IN) + (size_t)b0 * D_IN;
    const float* nb1   = nb0 + (size_t)NB * D_IN;

    // ---- pack phase: 49 passes, x loaded once per pass ----
    {
        f32x4 xA, n0A, n1A;
        {
            const size_t fo = (size_t)tid * 4;
            xA  = ld(xb + fo);
            n0A = ldnt(nb0 + fo);
            n1A = ldnt(nb1 + fo);
        }
        #pragma unroll 2
        for (int p = 0; p < 49; ++p) {
            const f32x4 xC = xA, n0C = n0A, n1C = n1A;
            if (p < 48) {
                const size_t fo = (size_t)(p + 1) * 2048 + (size_t)tid * 4;
                xA  = ld(xb + fo);
                n0A = ldnt(nb0 + fo);
                n1A = ldnt(nb1 + fo);
            }
            const unsigned long long a0 = __ballot(n0C[0] < xC[0]);
            const unsigned long long a1 = __ballot(n0C[1] < xC[1]);
            const unsigned long long a2 = __ballot(n0C[2] < xC[2]);
            const unsigned long long a3 = __ballot(n0C[3] < xC[3]);
            const unsigned long long c0 = __ballot(n1C[0] < xC[0]);
            const unsigned long long c1 = __ballot(n1C[1] < xC[1]);
            const unsigned long long c2 = __ballot(n1C[2] < xC[2]);
            const unsigned long long c3 = __ballot(n1C[3] < xC[3]);
            if (lane < 16) {
                const int g = p * 128 + wave * 16 + u;            // < 6272
                const uint32_t row = ((uint32_t)g * 42800u) >> 21; // g/49 exact
                const int off = (int)row * 50 + (g - (int)row * 49);
                const uint32_t v0 = (uint32_t)((a0 >> (4 * u)) & 15ull)
                                  | ((uint32_t)((a1 >> (4 * u)) & 15ull) << 4)
                                  | ((uint32_t)((a2 >> (4 * u)) & 15ull) << 8)
                                  | ((uint32_t)((a3 >> (4 * u)) & 15ull) << 12);
                const uint32_t v1 = (uint32_t)((c0 >> (4 * u)) & 15ull)
                                  | ((uint32_t)((c1 >> (4 * u)) & 15ull) << 4)
                                  | ((uint32_t)((c2 >> (4 * u)) & 15ull) << 8)
                                  | ((uint32_t)((c3 >> (4 * u)) & 15ull) << 12);
                sB[0][off] = (unsigned short)v0;
                sB[1][off] = (unsigned short)v1;
            }
        }
    }
    __syncthreads();

    // ---- GEMM phase: wf fragment loaded once per kt, used for both t's ----
    const uint32_t* s0 = reinterpret_cast<const uint32_t*>(&sB[0][0]);
    const uint32_t* s1 = reinterpret_cast<const uint32_t*>(&sB[1][0]);
    const int qe0 = (lg & 1) * 2 + (lg >> 1) * 16;
    const int rowBase = (Mhalf * 64 + u) * 25;

    f32x4 acc[2][4][2];
    #pragma unroll
    for (int tt = 0; tt < 2; ++tt)
        #pragma unroll
        for (int mt = 0; mt < 4; ++mt)
            #pragma unroll
            for (int nt = 0; nt < 2; ++nt) acc[tt][mt][nt] = (f32x4){0, 0, 0, 0};

    #pragma unroll 2
    for (int kt = 0; kt < KT; ++kt) {
        bf16x8 bhi[2], blo[2];
        #pragma unroll
        for (int nt = 0; nt < 2; ++nt) {
            const size_t fo = (size_t)(kt * 8 + Nq * 2 + nt) * 1024 + lane * 8;
            bhi[nt] = *reinterpret_cast<const bf16x8*>(wf + fo);
            blo[nt] = *reinterpret_cast<const bf16x8*>(wf + fo + 512);
        }
        #pragma unroll
        for (int mt = 0; mt < 4; ++mt) {
            const int ro = rowBase + mt * 400 + kt;    // (Mhalf*64+mt*16+u)*25 + kt
            const uint32_t g0 = s0[ro];
            const uint32_t g1 = s1[ro];
            union { uint32_t uu[4]; bf16x8 vv; } pk0, pk1;
            #pragma unroll
            for (int d = 0; d < 4; ++d) {
                const int qe = qe0 + (d & 1) * 8 + (d >> 1);
                pk0.uu[d] = ((g0 >> qe) & 1u) * 0x3F80u | ((g0 >> (qe + 4)) & 1u) * 0x3F800000u;
                pk1.uu[d] = ((g1 >> qe) & 1u) * 0x3F80u | ((g1 >> (qe + 4)) & 1u) * 0x3F800000u;
            }
            #pragma unroll
            for (int nt = 0; nt < 2; ++nt) {
                acc[0][mt][nt] = __builtin_amdgcn_mfma_f32_16x16x32_bf16(pk0.vv, bhi[nt], acc[0][mt][nt], 0, 0, 0);
                acc[0][mt][nt] = __builtin_amdgcn_mfma_f32_16x16x32_bf16(pk0.vv, blo[nt], acc[0][mt][nt], 0, 0, 0);
                acc[1][mt][nt] = __builtin_amdgcn_mfma_f32_16x16x32_bf16(pk1.vv, bhi[nt], acc[1][mt][nt], 0, 0, 0);
                acc[1][mt][nt] = __builtin_amdgcn_mfma_f32_16x16x32_bf16(pk1.vv, blo[nt], acc[1][mt][nt], 0, 0, 0);
            }
        }
    }

    // ---- epilogue: H transposed [b][t][100]. C/D: col=u, row=lg*4+r ----
    #pragma unroll
    for (int tt = 0; tt < 2; ++tt) {
        const int t = 2 * tp + tt;
        #pragma unroll
        for (int mt = 0; mt < 4; ++mt) {
            const int rowG = b0 + Mhalf * 64 + mt * 16 + lg * 4;
            #pragma unroll
            for (int nt = 0; nt < 2; ++nt) {
                const int col = (Nq * 2 + nt) * 16 + u;
                if (col < DH) {
                    #pragma unroll
                    for (int r = 0; r < 4; ++r)
                        H[(size_t)(rowG + r) * (32 * DH) + t * DH + col] = acc[tt][mt][nt][r];
                }
            }
        }
    }
}

// ---------------- K2: IF scan over t + logits = cnt @ W2^T ----------------
// H transposed: row b = 3200 consecutive floats (t-major).
__global__ __launch_bounds__(256) void snn_scan(const float* __restrict__ H,
                                                const float* __restrict__ W2,
                                                float* __restrict__ out) {
    __shared__ float cbuf[2][104];
    __shared__ float w2s[1000];
    const int tid = threadIdx.x;
    const int r = tid >> 7, h = tid & 127;
    const size_t b = (size_t)blockIdx.x * 2 + r;
    for (int i = tid; i < 1000; i += 256) w2s[i] = W2[i];

    float cnt = 0.f;
    if (h < DH) {
        float hv[32];
        #pragma unroll
        for (int t = 0; t < 32; ++t) hv[t] = H[b * (32 * DH) + t * DH + h];
        float v = 0.f;
        #pragma unroll
        for (int t = 0; t < 32; ++t) {
            v += hv[t];
            float s = (v - 1.0f > 0.0f) ? 1.0f : 0.0f;  // exact reference semantics
            v -= s;
            cnt += s;
        }
    }
    if (h < DH) cbuf[r][h] = cnt;
    __syncthreads();
    if (tid < 20) {
        const int rr = tid / 10, o = tid % 10;
        float s = 0.f;
        for (int hh = 0; hh < DH; ++hh) s += cbuf[rr][hh] * w2s[o * DH + hh];
        out[((size_t)blockIdx.x * 2 + rr) * 10 + o] = s;
    }
}

extern "C" void kernel_launch(void* const* d_in, const int* in_sizes, int n_in,
                              void* d_out, int out_size, void* d_ws, size_t ws_size,
                              hipStream_t stream) {
    const float* x     = (const float*)d_in[0];   // [8192,784]
    const float* noise = (const float*)d_in[1];   // [32,8192,784]
    const float* W1    = (const float*)d_in[2];   // [100,784]
    const float* W2    = (const float*)d_in[3];   // [10,100]
    float* out = (float*)d_out;                   // [8192,10]

    unsigned short* wf = (unsigned short*)d_ws;                      // 400 KB W1 frags
    float* H = (float*)((char*)d_ws + (1u << 20));                   // 104.9 MB H (transposed)

    prep_w1<<<50, 256, 0, stream>>>(W1, wf);
    snn_gemm2<<<1024, 512, 0, stream>>>(x, noise, wf, H);
    snn_scan<<<4096, 256, 0, stream>>>(H, W2, out);
}